// Round 9
// baseline (137.208 us; speedup 1.0000x reference)
//
#include <hip/hip_runtime.h>
#include <hip/hip_bf16.h>

// FractalTransformer fused kernels, round 9.
// vs r8 (102us attn, stuck): M_wave=64's ~240-reg live set forced ~110 regs
// into AGPRs (VGPR_Count pinned at 128) -> accvgpr_read/write on every
// update access + only ~2 waves/SIMD to hide L2 latency. Retreat to
// M_wave=32 (afrag[2][8] = 64 VGPR, live ~150): genuinely in-register,
// launch_bounds(256,3) -> 3 waves/SIMD. Cost: k fragment stream read by 2x
// the waves (2.1GB via L1/L2; kfrag 512KB is L2-resident, co-resident waves
// L1-dedupe). Grid 2048 = b x sq x e-half; slice = eh*4+wv owns 32 e;
// v repacked at 32-e granularity. Same no-max swishmax + prefetch placement.

typedef __attribute__((ext_vector_type(8))) short short8;
typedef __attribute__((ext_vector_type(4))) float f32x4;
typedef __attribute__((ext_vector_type(8))) _Float16 half8;
typedef __attribute__((ext_vector_type(4))) _Float16 half4;

#define DD 256
#define SS 512
#define LOG2E 1.4426950408889634f
#define LN2   0.6931471805599453f

__device__ __forceinline__ unsigned short f2bf(float f) {
  unsigned int b = __float_as_uint(f);
  b += 0x7FFFu + ((b >> 16) & 1u);   // RNE
  return (unsigned short)(b >> 16);
}
__device__ __forceinline__ short8 cvt8(f32x4 lo, f32x4 hi) {
  short8 r;
  r[0]=(short)f2bf(lo[0]); r[1]=(short)f2bf(lo[1]);
  r[2]=(short)f2bf(lo[2]); r[3]=(short)f2bf(lo[3]);
  r[4]=(short)f2bf(hi[0]); r[5]=(short)f2bf(hi[1]);
  r[6]=(short)f2bf(hi[2]); r[7]=(short)f2bf(hi[3]);
  return r;
}

// ------------------------------------------------------------------
// One-time: bf16-convert 6 weights; (w_al + I) -> f16. out = 7 x [256][256].
// ------------------------------------------------------------------
__global__ __launch_bounds__(256) void prep_weights(
    const float* __restrict__ w0, const float* __restrict__ w1,
    const float* __restrict__ w2, const float* __restrict__ w3,
    const float* __restrict__ w4, const float* __restrict__ w5,
    const float* __restrict__ wal, unsigned short* __restrict__ out)
{
  const int bi = blockIdx.x;               // 7*32
  const int m = bi >> 5;
  const int off = ((bi & 31) * 256 + threadIdx.x) * 8;
  const float* src = m==0?w0: m==1?w1: m==2?w2: m==3?w3: m==4?w4: m==5?w5: wal;
  f32x4 a = *(const f32x4*)(src + off);
  f32x4 b = *(const f32x4*)(src + off + 4);
  if (m == 6) {                            // fold residual (+I), store f16
    const int e = off >> 8, d = off & 255;
#pragma unroll
    for (int jj = 0; jj < 4; ++jj) {
      if (e == d + jj)     a[jj] += 1.0f;
      if (e == d + 4 + jj) b[jj] += 1.0f;
    }
    half8 h;
#pragma unroll
    for (int jj = 0; jj < 4; ++jj) {
      h[jj]     = (_Float16)a[jj];
      h[jj + 4] = (_Float16)b[jj];
    }
    *(half8*)(out + (size_t)m * 65536 + off) = h;
  } else {
    *(short8*)(out + (size_t)m * 65536 + off) = cvt8(a, b);
  }
}

// ------------------------------------------------------------------
// out[1024,256] = A @ Wbf^T (+res1)(+res2). grid 256 = 64 rowblk x 4 colblk.
// ------------------------------------------------------------------
__global__ __launch_bounds__(256) void linear_bf(
    const float* __restrict__ A, const unsigned short* __restrict__ Wbf,
    const float* __restrict__ res1, const float* __restrict__ res2,
    float* __restrict__ out)
{
  const int bi = blockIdx.x;
  const int rb = (bi >> 2) * 16;
  const int cb = (bi & 3) * 64;
  const int tid = threadIdx.x;
  const int wv = tid >> 6, lane = tid & 63;
  const int g = lane >> 4, c = lane & 15;
  const int arow = rb + c;
  const int wrow = cb + wv * 16 + c;

  f32x4 acc = (f32x4){0.f, 0.f, 0.f, 0.f};
#pragma unroll
  for (int ks = 0; ks < 8; ++ks) {
    const int d0 = ks * 32 + g * 8;
    f32x4 a0 = *(const f32x4*)(A + arow * DD + d0);
    f32x4 a1 = *(const f32x4*)(A + arow * DD + d0 + 4);
    short8 av = cvt8(a0, a1);
    short8 bv = *(const short8*)(Wbf + wrow * DD + d0);
    acc = __builtin_amdgcn_mfma_f32_16x16x32_bf16(av, bv, acc, 0, 0, 0);
  }
#pragma unroll
  for (int j = 0; j < 4; ++j) {
    const int ro = rb + g * 4 + j;
    const int co = cb + wv * 16 + c;
    float v = acc[j];
    if (res1) v += res1[ro * DD + co];
    if (res2) v += res2[ro * DD + co];
    out[ro * DD + co] = v;
  }
}

// ------------------------------------------------------------------
// q = f16((X + X@Wq^T)*log2e);  k,v = f16(X + X@{Wk,Wv}^T)
// ------------------------------------------------------------------
__global__ __launch_bounds__(256) void linear_qkv(
    const float* __restrict__ X,
    const unsigned short* __restrict__ Wq, const unsigned short* __restrict__ Wk,
    const unsigned short* __restrict__ Wv,
    _Float16* __restrict__ qout, _Float16* __restrict__ kout,
    _Float16* __restrict__ vout)
{
  const int bi = blockIdx.x;
  const int rb = (bi >> 2) * 16;
  const int cb = (bi & 3) * 64;
  const int tid = threadIdx.x;
  const int wv = tid >> 6, lane = tid & 63;
  const int g = lane >> 4, c = lane & 15;
  const int arow = rb + c;
  const int wrow = cb + wv * 16 + c;

  f32x4 aq = (f32x4){0.f,0.f,0.f,0.f};
  f32x4 ak = (f32x4){0.f,0.f,0.f,0.f};
  f32x4 av_ = (f32x4){0.f,0.f,0.f,0.f};
#pragma unroll
  for (int ks = 0; ks < 8; ++ks) {
    const int d0 = ks * 32 + g * 8;
    f32x4 a0 = *(const f32x4*)(X + arow * DD + d0);
    f32x4 a1 = *(const f32x4*)(X + arow * DD + d0 + 4);
    short8 af = cvt8(a0, a1);
    short8 bq = *(const short8*)(Wq + wrow * DD + d0);
    aq = __builtin_amdgcn_mfma_f32_16x16x32_bf16(af, bq, aq, 0, 0, 0);
    short8 bk = *(const short8*)(Wk + wrow * DD + d0);
    ak = __builtin_amdgcn_mfma_f32_16x16x32_bf16(af, bk, ak, 0, 0, 0);
    short8 bv = *(const short8*)(Wv + wrow * DD + d0);
    av_ = __builtin_amdgcn_mfma_f32_16x16x32_bf16(af, bv, av_, 0, 0, 0);
  }
#pragma unroll
  for (int j = 0; j < 4; ++j) {
    const int ro = rb + g * 4 + j;
    const int co = cb + wv * 16 + c;
    const float base = X[ro * DD + co];
    qout[ro * DD + co] = (_Float16)((base + aq[j]) * LOG2E);
    kout[ro * DD + co] = (_Float16)(base + ak[j]);
    vout[ro * DD + co] = (_Float16)(base + av_[j]);
  }
}

// ------------------------------------------------------------------
// Pack k,v (f16, [b][s][d]) into fragment order.
// k (ids 0..32767): id = b*16384 + t2*512 + ks*64 + lane -> 8 f16:
//   k[b][t2*16 + (lane&15)][ks*32 + (lane>>4)*8 + 0..7]
// v (ids 32768..98303): id2 = b*32768 + t2*1024 + slice*128 + i*64 + lane
//   -> 4 f16: v[b][t2*16 + (lane&15)][slice*32 + i*16 + (lane>>4)*4 + 0..3]
// ------------------------------------------------------------------
__global__ __launch_bounds__(256) void pack_kv(
    const _Float16* __restrict__ k, const _Float16* __restrict__ v,
    _Float16* __restrict__ kfrag, _Float16* __restrict__ vfrag)
{
  const int id = blockIdx.x * 256 + threadIdx.x;   // 98304
  if (id < 32768) {
    const int lane = id & 63, ks = (id >> 6) & 7, t2 = (id >> 9) & 31, b = id >> 14;
    const int g = lane >> 4, c = lane & 15;
    const _Float16* src = k + ((size_t)(b * SS + t2 * 16 + c) * DD + ks * 32 + g * 8);
    *(half8*)(kfrag + (size_t)id * 8) = *(const half8*)src;
  } else {
    const int id2 = id - 32768;                    // 0..65535
    const int lane = id2 & 63, i = (id2 >> 6) & 1, slice = (id2 >> 7) & 7,
              t2 = (id2 >> 10) & 31, b = id2 >> 15;
    const int g = lane >> 4, c = lane & 15;
    const _Float16* src = v + ((size_t)(b * SS + t2 * 16 + c) * DD + slice * 32 + i * 16 + g * 4);
    *(half4*)(vfrag + (size_t)id2 * 4) = *(const half4*)src;
  }
}

// ------------------------------------------------------------------
// Fused fractal attention v9. Grid 2048 = b x sq x eh; 4 waves (256 thr).
// slice = eh*4+wv owns e in [slice*32, +32). afrag[2][8] = 64 VGPR ->
// whole kernel fits arch VGPRs at 3 waves/SIMD (launch_bounds(256,3)).
// No LDS/barriers; k/v fragment-packed global streams (L2-resident).
// ------------------------------------------------------------------
__global__ __launch_bounds__(256, 3) void fractal_attn(
    const _Float16* __restrict__ walI,   // f16 (wal+I), [256][256]
    const _Float16* __restrict__ qf,     // f16, pre-scaled by log2e
    const _Float16* __restrict__ kfrag,
    const _Float16* __restrict__ vfrag,
    float* __restrict__ vsum)
{
  const int bid = blockIdx.x;            // 2048
  const int eh = bid & 1;
  const int sq = (bid >> 1) & 511;
  const int b  = bid >> 10;
  const int tid = threadIdx.x;
  const int wv = tid >> 6;
  const int lane = tid & 63;
  const int g = lane >> 4, c = lane & 15;
  const int slice = eh * 4 + wv;
  const int sbase = slice * 32;

  // ---- A' fragments: wave owns e in [sbase, sbase+32) ----
  half8 afrag[2][8];
  {
    const _Float16* qrow = qf + (size_t)(b * SS + sq) * DD;
    half8 q8[8];
#pragma unroll
    for (int ks = 0; ks < 8; ++ks)
      q8[ks] = *(const half8*)(qrow + ks * 32 + g * 8);
#pragma unroll
    for (int i = 0; i < 2; ++i) {
      const int e = sbase + i * 16 + c;
      const _Float16* wrow = walI + (size_t)e * DD;
#pragma unroll
      for (int ks = 0; ks < 8; ++ks)
        afrag[i][ks] = (*(const half8*)(wrow + ks * 32 + g * 8)) * q8[ks];
    }
  }

  // ---- fragment stream bases ----
  const _Float16* kfb = kfrag + (size_t)b * 131072 + lane * 8;       // + t2*4096 + ks*512
  const _Float16* vfb = vfrag + ((size_t)(b * 256 + slice) * 2) * 256 + lane * 4;  // + t2*4096 + i*256

  // ---- state: 8 e-slots per lane (e = sbase + i*16 + g*4 + j) ----
  float mst[8], sst[8], vst[8];
#pragma unroll
  for (int s = 0; s < 8; ++s) { mst[s] = -1e30f; sst[s] = 0.f; vst[s] = 0.f; }

  half8 bf[8];
  half4 vq[2];
  f32x4 acc[2];
  const f32x4 zeroc = (f32x4){0.f, 0.f, 0.f, 0.f};

  // ---- prologue: tile 0 loads ----
#pragma unroll
  for (int ks = 0; ks < 8; ++ks) bf[ks] = *(const half8*)(kfb + ks * 512);
  vq[0] = *(const half4*)(vfb);
  vq[1] = *(const half4*)(vfb + 256);

#pragma unroll 1
  for (int t2 = 0; t2 < 32; ++t2) {
    // ---- MFMA cluster (16 MFMAs, 2 independent acc chains) ----
    __builtin_amdgcn_s_setprio(1);
    acc[0] = __builtin_amdgcn_mfma_f32_16x16x32_f16(afrag[0][0], bf[0], zeroc, 0, 0, 0);
    acc[1] = __builtin_amdgcn_mfma_f32_16x16x32_f16(afrag[1][0], bf[0], zeroc, 0, 0, 0);
#pragma unroll
    for (int ks = 1; ks < 8; ++ks) {
      acc[0] = __builtin_amdgcn_mfma_f32_16x16x32_f16(afrag[0][ks], bf[ks], acc[0], 0, 0, 0);
      acc[1] = __builtin_amdgcn_mfma_f32_16x16x32_f16(afrag[1][ks], bf[ks], acc[1], 0, 0, 0);
    }
    __builtin_amdgcn_s_setprio(0);

    // ---- prefetch next k tile in place (bf dead after MFMA issue) ----
    if (t2 < 31) {
      const _Float16* kf_ = kfb + (t2 + 1) * 4096;
#pragma unroll
      for (int ks = 0; ks < 8; ++ks) bf[ks] = *(const half8*)(kf_ + ks * 512);
    }

    // ---- online update: slot s = i*4+j; sk = t2*16 + c ----
#pragma unroll
    for (int i = 0; i < 2; ++i) {
#pragma unroll
      for (int j = 0; j < 4; ++j) {
        const int s = i * 4 + j;
        const float L = acc[i][j];
        mst[s] = fmaxf(mst[s], L);
        const float p = L * __builtin_amdgcn_exp2f(L);
        sst[s] += fabsf(p);
        vst[s] = fmaf((float)vq[i][j], p, vst[s]);
      }
    }

    // ---- prefetch next v tile (vq dead after update) ----
    if (t2 < 31) {
      const _Float16* vf_ = vfb + (t2 + 1) * 4096;
      vq[0] = *(const half4*)(vf_);
      vq[1] = *(const half4*)(vf_ + 256);
    }
  }

  // ---- merge across the 16 sk-lanes (same g => same e) ----
#pragma unroll
  for (int mask = 1; mask <= 8; mask <<= 1) {
#pragma unroll
    for (int s = 0; s < 8; ++s) {
      mst[s] = fmaxf(mst[s], __shfl_xor(mst[s], mask));
      sst[s] += __shfl_xor(sst[s], mask);
      vst[s] += __shfl_xor(vst[s], mask);
    }
  }

  if (c == 0) {
    float* orow = vsum + (size_t)(b * SS + sq) * DD;
#pragma unroll
    for (int i = 0; i < 2; ++i) {
      f32x4 o;
#pragma unroll
      for (int j = 0; j < 4; ++j) {
        const int s = i * 4 + j;
        const float tt = LN2 * __builtin_amdgcn_exp2f(-mst[s]);
        o[j] = vst[s] * tt / (sst[s] * tt + 1.0f);
      }
      *(f32x4*)(orow + sbase + i * 16 + g * 4) = o;
    }
  }
}

// ------------------------------------------------------------------
extern "C" void kernel_launch(void* const* d_in, const int* in_sizes, int n_in,
                              void* d_out, int out_size, void* d_ws, size_t ws_size,
                              hipStream_t stream) {
  const float* x     = (const float*)d_in[0];
  const float* w_pre = (const float*)d_in[1];
  const float* w_q   = (const float*)d_in[2];
  const float* w_k   = (const float*)d_in[3];
  const float* w_va  = (const float*)d_in[4];
  const float* w_al  = (const float*)d_in[5];
  const float* w_vo  = (const float*)d_in[6];
  const float* w_end = (const float*)d_in[7];
  float* out = (float*)d_out;

  char* ws = (char*)d_ws;
  float*    X     = (float*)(ws);                         // 1MB
  float*    Y     = (float*)(ws + (1 << 20));             // 1MB
  float*    vsum  = (float*)(ws + (2 << 20));             // 1MB
  _Float16* qf16  = (_Float16*)(ws + (3 << 20));          // 512KB
  _Float16* kf16  = (_Float16*)(ws + (3 << 20) + (512 << 10));
  _Float16* vf16  = (_Float16*)(ws + (4 << 20));
  _Float16* kfrag = (_Float16*)(ws + (4 << 20) + (512 << 10));  // 512KB
  _Float16* vfrag = (_Float16*)(ws + (5 << 20));                // 512KB
  unsigned short* wbf = (unsigned short*)(ws + (5 << 20) + (512 << 10));
  // wbf order: pre, q, k, va, vo, end, walI(+I, f16)

  prep_weights<<<224, 256, 0, stream>>>(w_pre, w_q, w_k, w_va, w_vo, w_end,
                                        w_al, wbf);
  linear_bf<<<256, 256, 0, stream>>>(x, wbf + 0 * 65536, nullptr, nullptr, X);
  linear_qkv<<<256, 256, 0, stream>>>(X, wbf + 1 * 65536, wbf + 2 * 65536,
                                      wbf + 3 * 65536, qf16, kf16, vf16);
  pack_kv<<<384, 256, 0, stream>>>(kf16, vf16, kfrag, vfrag);
  fractal_attn<<<2048, 256, 0, stream>>>((const _Float16*)(wbf + 6 * 65536),
                                         qf16, kfrag, vfrag, vsum);
  linear_bf<<<256, 256, 0, stream>>>(vsum, wbf + 4 * 65536, vsum, X, Y);
  linear_bf<<<256, 256, 0, stream>>>(Y, wbf + 5 * 65536, nullptr, nullptr, out);
}

// Round 10
// 123.986 us; speedup vs baseline: 1.1066x; 1.1066x over previous
//
#include <hip/hip_runtime.h>
#include <hip/hip_bf16.h>

// FractalTransformer fused kernels, round 10.
// vs r6/r8 (102us attn plateau): evidence says latency-bound with the k
// fragment stream multicast through L2 (~1.3GB same-line traffic) as the
// uncovered latency. Fix: kfrag is fragment-LINEAR, so stage each 8KB k
// tile into LDS with a straight global_load_lds copy (no swizzle), double
// buffered 2x8KB; all 4 waves (full 256 e, M_wave=64 as r8) broadcast-read
// via conflict-free ds_read_b128. k L2 traffic: 1GB -> 256MB one-shot.
// v becomes f32 fragments (kills 16 v_cvt/tile in the update). One
// __syncthreads per tile; stage(t+1) issued ~1.5K cycles before its drain.

typedef __attribute__((ext_vector_type(8))) short short8;
typedef __attribute__((ext_vector_type(4))) float f32x4;
typedef __attribute__((ext_vector_type(8))) _Float16 half8;
typedef __attribute__((ext_vector_type(4))) _Float16 half4;

#define DD 256
#define SS 512
#define LOG2E 1.4426950408889634f
#define LN2   0.6931471805599453f

__device__ __forceinline__ unsigned short f2bf(float f) {
  unsigned int b = __float_as_uint(f);
  b += 0x7FFFu + ((b >> 16) & 1u);   // RNE
  return (unsigned short)(b >> 16);
}
__device__ __forceinline__ short8 cvt8(f32x4 lo, f32x4 hi) {
  short8 r;
  r[0]=(short)f2bf(lo[0]); r[1]=(short)f2bf(lo[1]);
  r[2]=(short)f2bf(lo[2]); r[3]=(short)f2bf(lo[3]);
  r[4]=(short)f2bf(hi[0]); r[5]=(short)f2bf(hi[1]);
  r[6]=(short)f2bf(hi[2]); r[7]=(short)f2bf(hi[3]);
  return r;
}
__device__ __forceinline__ void gload16(const void* g, void* l) {
  __builtin_amdgcn_global_load_lds(
      (const __attribute__((address_space(1))) void*)g,
      (__attribute__((address_space(3))) void*)l,
      16, 0, 0);
}

// ------------------------------------------------------------------
// One-time: bf16-convert 6 weights; (w_al + I) -> f16. out = 7 x [256][256].
// ------------------------------------------------------------------
__global__ __launch_bounds__(256) void prep_weights(
    const float* __restrict__ w0, const float* __restrict__ w1,
    const float* __restrict__ w2, const float* __restrict__ w3,
    const float* __restrict__ w4, const float* __restrict__ w5,
    const float* __restrict__ wal, unsigned short* __restrict__ out)
{
  const int bi = blockIdx.x;               // 7*32
  const int m = bi >> 5;
  const int off = ((bi & 31) * 256 + threadIdx.x) * 8;
  const float* src = m==0?w0: m==1?w1: m==2?w2: m==3?w3: m==4?w4: m==5?w5: wal;
  f32x4 a = *(const f32x4*)(src + off);
  f32x4 b = *(const f32x4*)(src + off + 4);
  if (m == 6) {                            // fold residual (+I), store f16
    const int e = off >> 8, d = off & 255;
#pragma unroll
    for (int jj = 0; jj < 4; ++jj) {
      if (e == d + jj)     a[jj] += 1.0f;
      if (e == d + 4 + jj) b[jj] += 1.0f;
    }
    half8 h;
#pragma unroll
    for (int jj = 0; jj < 4; ++jj) {
      h[jj]     = (_Float16)a[jj];
      h[jj + 4] = (_Float16)b[jj];
    }
    *(half8*)(out + (size_t)m * 65536 + off) = h;
  } else {
    *(short8*)(out + (size_t)m * 65536 + off) = cvt8(a, b);
  }
}

// ------------------------------------------------------------------
// out[1024,256] = A @ Wbf^T (+res1)(+res2). grid 256 = 64 rowblk x 4 colblk.
// ------------------------------------------------------------------
__global__ __launch_bounds__(256) void linear_bf(
    const float* __restrict__ A, const unsigned short* __restrict__ Wbf,
    const float* __restrict__ res1, const float* __restrict__ res2,
    float* __restrict__ out)
{
  const int bi = blockIdx.x;
  const int rb = (bi >> 2) * 16;
  const int cb = (bi & 3) * 64;
  const int tid = threadIdx.x;
  const int wv = tid >> 6, lane = tid & 63;
  const int g = lane >> 4, c = lane & 15;
  const int arow = rb + c;
  const int wrow = cb + wv * 16 + c;

  f32x4 acc = (f32x4){0.f, 0.f, 0.f, 0.f};
#pragma unroll
  for (int ks = 0; ks < 8; ++ks) {
    const int d0 = ks * 32 + g * 8;
    f32x4 a0 = *(const f32x4*)(A + arow * DD + d0);
    f32x4 a1 = *(const f32x4*)(A + arow * DD + d0 + 4);
    short8 av = cvt8(a0, a1);
    short8 bv = *(const short8*)(Wbf + wrow * DD + d0);
    acc = __builtin_amdgcn_mfma_f32_16x16x32_bf16(av, bv, acc, 0, 0, 0);
  }
#pragma unroll
  for (int j = 0; j < 4; ++j) {
    const int ro = rb + g * 4 + j;
    const int co = cb + wv * 16 + c;
    float v = acc[j];
    if (res1) v += res1[ro * DD + co];
    if (res2) v += res2[ro * DD + co];
    out[ro * DD + co] = v;
  }
}

// ------------------------------------------------------------------
// q = f16((X + X@Wq^T)*log2e);  k = f16(X + X@Wk^T);  v = f32(X + X@Wv^T)
// ------------------------------------------------------------------
__global__ __launch_bounds__(256) void linear_qkv(
    const float* __restrict__ X,
    const unsigned short* __restrict__ Wq, const unsigned short* __restrict__ Wk,
    const unsigned short* __restrict__ Wv,
    _Float16* __restrict__ qout, _Float16* __restrict__ kout,
    float* __restrict__ vout)
{
  const int bi = blockIdx.x;
  const int rb = (bi >> 2) * 16;
  const int cb = (bi & 3) * 64;
  const int tid = threadIdx.x;
  const int wv = tid >> 6, lane = tid & 63;
  const int g = lane >> 4, c = lane & 15;
  const int arow = rb + c;
  const int wrow = cb + wv * 16 + c;

  f32x4 aq = (f32x4){0.f,0.f,0.f,0.f};
  f32x4 ak = (f32x4){0.f,0.f,0.f,0.f};
  f32x4 av_ = (f32x4){0.f,0.f,0.f,0.f};
#pragma unroll
  for (int ks = 0; ks < 8; ++ks) {
    const int d0 = ks * 32 + g * 8;
    f32x4 a0 = *(const f32x4*)(X + arow * DD + d0);
    f32x4 a1 = *(const f32x4*)(X + arow * DD + d0 + 4);
    short8 af = cvt8(a0, a1);
    short8 bq = *(const short8*)(Wq + wrow * DD + d0);
    aq = __builtin_amdgcn_mfma_f32_16x16x32_bf16(af, bq, aq, 0, 0, 0);
    short8 bk = *(const short8*)(Wk + wrow * DD + d0);
    ak = __builtin_amdgcn_mfma_f32_16x16x32_bf16(af, bk, ak, 0, 0, 0);
    short8 bv = *(const short8*)(Wv + wrow * DD + d0);
    av_ = __builtin_amdgcn_mfma_f32_16x16x32_bf16(af, bv, av_, 0, 0, 0);
  }
#pragma unroll
  for (int j = 0; j < 4; ++j) {
    const int ro = rb + g * 4 + j;
    const int co = cb + wv * 16 + c;
    const float base = X[ro * DD + co];
    qout[ro * DD + co] = (_Float16)((base + aq[j]) * LOG2E);
    kout[ro * DD + co] = (_Float16)(base + ak[j]);
    vout[ro * DD + co] = base + av_[j];
  }
}

// ------------------------------------------------------------------
// Pack k (f16) and v (f32) into fragment order.
// k (ids 0..32767): id = b*16384 + t2*512 + ks*64 + lane -> 8 f16:
//   k[b][t2*16 + (lane&15)][ks*32 + (lane>>4)*8 + 0..7]
// v (ids 32768..98303): id2 = b*32768 + t2*1024 + wv*256 + i*64 + lane
//   -> 4 f32: v[b][t2*16 + (lane&15)][wv*64 + i*16 + (lane>>4)*4 + 0..3]
// ------------------------------------------------------------------
__global__ __launch_bounds__(256) void pack_kv(
    const _Float16* __restrict__ k, const float* __restrict__ v,
    _Float16* __restrict__ kfrag, float* __restrict__ vfrag)
{
  const int id = blockIdx.x * 256 + threadIdx.x;   // 98304
  if (id < 32768) {
    const int lane = id & 63, ks = (id >> 6) & 7, t2 = (id >> 9) & 31, b = id >> 14;
    const int g = lane >> 4, c = lane & 15;
    const _Float16* src = k + ((size_t)(b * SS + t2 * 16 + c) * DD + ks * 32 + g * 8);
    *(half8*)(kfrag + (size_t)id * 8) = *(const half8*)src;
  } else {
    const int id2 = id - 32768;                    // 0..65535
    const int lane = id2 & 63, i = (id2 >> 6) & 3, wv = (id2 >> 8) & 3,
              t2 = (id2 >> 10) & 31, b = id2 >> 15;
    const int g = lane >> 4, c = lane & 15;
    const float* src = v + ((size_t)(b * SS + t2 * 16 + c) * DD + wv * 64 + i * 16 + g * 4);
    *(f32x4*)(vfrag + (size_t)id2 * 4) = *(const f32x4*)src;
  }
}

// ------------------------------------------------------------------
// Fused fractal attention v10. Grid 1024 = b x sq; 4 waves (256 thr).
// Wave wv owns e in [wv*64, +64) (M_wave=64). k tile (8KB, fragment-
// linear) staged to LDS once per block via straight global_load_lds copy,
// double-buffered; all 4 waves ds_read_b128 it conflict-free. v read as
// f32 fragments from global (per-wave slices, no multicast).
// ------------------------------------------------------------------
__global__ __launch_bounds__(256, 2) void fractal_attn(
    const _Float16* __restrict__ walI,   // f16 (wal+I), [256][256]
    const _Float16* __restrict__ qf,     // f16, pre-scaled by log2e
    const _Float16* __restrict__ kfrag,  // f16 fragment-packed
    const float* __restrict__ vfrag,     // f32 fragment-packed
    float* __restrict__ vsum)
{
  __shared__ _Float16 kt[2][4096];       // 2 x 8KB k tiles

  const int bid = blockIdx.x;            // 1024
  const int sq = bid & 511;
  const int b  = bid >> 9;
  const int tid = threadIdx.x;
  const int wv = tid >> 6;
  const int lane = tid & 63;
  const int g = lane >> 4, c = lane & 15;

  // ---- k tile staging: straight linear copy, 256 thr x 2 x 16B = 8KB ----
  const _Float16* ktile0 = kfrag + (size_t)b * 131072;   // + t2*4096 halfs
  auto stage = [&](int t) {
    const _Float16* src = ktile0 + (size_t)t * 4096;
    _Float16* dst = &kt[t & 1][0];
    gload16(src + tid * 8,         dst + tid * 8);
    gload16(src + 2048 + tid * 8,  dst + 2048 + tid * 8);
  };

  stage(0);   // oldest in vmcnt; completes while we build A'

  // ---- A' fragments: wave owns e in [wv*64, wv*64+64) ----
  half8 afrag[4][8];
  {
    const _Float16* qrow = qf + (size_t)(b * SS + sq) * DD;
    half8 q8[8];
#pragma unroll
    for (int ks = 0; ks < 8; ++ks)
      q8[ks] = *(const half8*)(qrow + ks * 32 + g * 8);
#pragma unroll
    for (int i = 0; i < 4; ++i) {
      const int e = wv * 64 + i * 16 + c;
      const _Float16* wrow = walI + (size_t)e * DD;
#pragma unroll
      for (int ks = 0; ks < 8; ++ks)
        afrag[i][ks] = (*(const half8*)(wrow + ks * 32 + g * 8)) * q8[ks];
    }
  }

  // ---- v fragment base (f32): float off = (b*512 + t2*16 + wv*4 + i)*256
  //      + lane*4 ----
  const float* vfb = vfrag + ((size_t)b * 512 + wv * 4) * 256 + lane * 4;

  // ---- state: 16 e-slots per lane (e = wv*64 + i*16 + g*4 + j) ----
  float mst[16], sst[16], vst[16];
#pragma unroll
  for (int s = 0; s < 16; ++s) { mst[s] = -1e30f; sst[s] = 0.f; vst[s] = 0.f; }

  half8 bf[8];
  f32x4 vq[4];
  f32x4 acc[4];
  const f32x4 zeroc = (f32x4){0.f, 0.f, 0.f, 0.f};

  __syncthreads();                       // tile 0 staged (drains stage(0))

#pragma unroll 1
  for (int t2 = 0; t2 < 32; ++t2) {
    if (t2 < 31) stage(t2 + 1);          // issue next k tile (oldest vm)

    // v loads for this tile (newer in vmcnt; used in update)
    const float* vf_ = vfb + (size_t)t2 * 4096;
#pragma unroll
    for (int i = 0; i < 4; ++i)
      vq[i] = *(const f32x4*)(vf_ + i * 256);

    // ---- LDS reads + MFMA cluster ----
    const _Float16* kb = &kt[t2 & 1][0];
    __builtin_amdgcn_s_setprio(1);
#pragma unroll
    for (int ks = 0; ks < 8; ++ks)
      bf[ks] = *(const half8*)(kb + ks * 512 + lane * 8);
#pragma unroll
    for (int i = 0; i < 4; ++i)
      acc[i] = __builtin_amdgcn_mfma_f32_16x16x32_f16(afrag[i][0], bf[0], zeroc, 0, 0, 0);
#pragma unroll
    for (int ks = 1; ks < 8; ++ks)
#pragma unroll
      for (int i = 0; i < 4; ++i)
        acc[i] = __builtin_amdgcn_mfma_f32_16x16x32_f16(afrag[i][ks], bf[ks], acc[i], 0, 0, 0);
    __builtin_amdgcn_s_setprio(0);

    // ---- online update: slot s = i*4+j; sk = t2*16 + c ----
#pragma unroll
    for (int i = 0; i < 4; ++i) {
#pragma unroll
      for (int j = 0; j < 4; ++j) {
        const int s = i * 4 + j;
        const float L = acc[i][j];
        mst[s] = fmaxf(mst[s], L);
        const float p = L * __builtin_amdgcn_exp2f(L);
        sst[s] += fabsf(p);
        vst[s] = fmaf(vq[i][j], p, vst[s]);
      }
    }

    __syncthreads();                     // stage(t2+1) done; swap buffers
  }

  // ---- merge across the 16 sk-lanes (same g => same e) ----
#pragma unroll
  for (int mask = 1; mask <= 8; mask <<= 1) {
#pragma unroll
    for (int s = 0; s < 16; ++s) {
      mst[s] = fmaxf(mst[s], __shfl_xor(mst[s], mask));
      sst[s] += __shfl_xor(sst[s], mask);
      vst[s] += __shfl_xor(vst[s], mask);
    }
  }

  if (c == 0) {
    float* orow = vsum + (size_t)(b * SS + sq) * DD;
#pragma unroll
    for (int i = 0; i < 4; ++i) {
      f32x4 o;
#pragma unroll
      for (int j = 0; j < 4; ++j) {
        const int s = i * 4 + j;
        const float tt = LN2 * __builtin_amdgcn_exp2f(-mst[s]);
        o[j] = vst[s] * tt / (sst[s] * tt + 1.0f);
      }
      *(f32x4*)(orow + wv * 64 + i * 16 + g * 4) = o;
    }
  }
}

// ------------------------------------------------------------------
extern "C" void kernel_launch(void* const* d_in, const int* in_sizes, int n_in,
                              void* d_out, int out_size, void* d_ws, size_t ws_size,
                              hipStream_t stream) {
  const float* x     = (const float*)d_in[0];
  const float* w_pre = (const float*)d_in[1];
  const float* w_q   = (const float*)d_in[2];
  const float* w_k   = (const float*)d_in[3];
  const float* w_va  = (const float*)d_in[4];
  const float* w_al  = (const float*)d_in[5];
  const float* w_vo  = (const float*)d_in[6];
  const float* w_end = (const float*)d_in[7];
  float* out = (float*)d_out;

  char* ws = (char*)d_ws;
  float*    X      = (float*)(ws);                              // 1MB
  float*    Y      = (float*)(ws + (1 << 20));                  // 1MB
  float*    vsum   = (float*)(ws + (2 << 20));                  // 1MB
  _Float16* qf16   = (_Float16*)(ws + (3 << 20));               // 512KB
  _Float16* kf16   = (_Float16*)(ws + (3 << 20) + (512 << 10)); // 512KB
  float*    vf32   = (float*)(ws + (4 << 20));                  // 1MB
  _Float16* kfrag  = (_Float16*)(ws + (5 << 20));               // 512KB
  float*    vfrag  = (float*)(ws + (5 << 20) + (512 << 10));    // 1MB
  unsigned short* wbf = (unsigned short*)(ws + (6 << 20) + (512 << 10)); // 896KB
  // wbf order: pre, q, k, va, vo, end, walI(+I, f16)

  prep_weights<<<224, 256, 0, stream>>>(w_pre, w_q, w_k, w_va, w_vo, w_end,
                                        w_al, wbf);
  linear_bf<<<256, 256, 0, stream>>>(x, wbf + 0 * 65536, nullptr, nullptr, X);
  linear_qkv<<<256, 256, 0, stream>>>(X, wbf + 1 * 65536, wbf + 2 * 65536,
                                      wbf + 3 * 65536, qf16, kf16, vf32);
  pack_kv<<<384, 256, 0, stream>>>(kf16, vf32, kfrag, vfrag);
  fractal_attn<<<1024, 256, 0, stream>>>((const _Float16*)(wbf + 6 * 65536),
                                         qf16, kfrag, vfrag, vsum);
  linear_bf<<<256, 256, 0, stream>>>(vsum, wbf + 4 * 65536, vsum, X, Y);
  linear_bf<<<256, 256, 0, stream>>>(Y, wbf + 5 * 65536, nullptr, nullptr, out);
}

// Round 11
// 120.533 us; speedup vs baseline: 1.1383x; 1.0286x over previous
//
#include <hip/hip_runtime.h>
#include <hip/hip_bf16.h>

// FractalTransformer fused kernels, round 11.
// r6/r8/r10 all = ~102us attn across 3 different k-paths => latency-bound
// per-wave serial stream at 2 waves/SIMD (M_wave=64 live ~250 regs caps
// occupancy at 2/SIMD on the 512-reg SIMD file; r7 proved no room to
// pipeline). New combo: M_wave=32 (live ~156 -> 3 waves/SIMD via
// launch_bounds(256,3)) + r10's LDS k-broadcast (absorbs the 2x fragment
// traffic on the LDS pipe, not L2 -- r9's mistake) + T15 accA/accB 2-tile
// pipeline (UPDATE(t-1) under MFMA(t), statically unrolled). Grid 2048 =
// b x sq x eh; 4 waves/block; slice=eh*4+wv owns 32 e. Spill tripwire:
// FETCH_SIZE must stay ~5MB.

typedef __attribute__((ext_vector_type(8))) short short8;
typedef __attribute__((ext_vector_type(4))) float f32x4;
typedef __attribute__((ext_vector_type(8))) _Float16 half8;
typedef __attribute__((ext_vector_type(4))) _Float16 half4;

#define DD 256
#define SS 512
#define LOG2E 1.4426950408889634f
#define LN2   0.6931471805599453f

__device__ __forceinline__ unsigned short f2bf(float f) {
  unsigned int b = __float_as_uint(f);
  b += 0x7FFFu + ((b >> 16) & 1u);   // RNE
  return (unsigned short)(b >> 16);
}
__device__ __forceinline__ short8 cvt8(f32x4 lo, f32x4 hi) {
  short8 r;
  r[0]=(short)f2bf(lo[0]); r[1]=(short)f2bf(lo[1]);
  r[2]=(short)f2bf(lo[2]); r[3]=(short)f2bf(lo[3]);
  r[4]=(short)f2bf(hi[0]); r[5]=(short)f2bf(hi[1]);
  r[6]=(short)f2bf(hi[2]); r[7]=(short)f2bf(hi[3]);
  return r;
}
__device__ __forceinline__ void gload16(const void* g, void* l) {
  __builtin_amdgcn_global_load_lds(
      (const __attribute__((address_space(1))) void*)g,
      (__attribute__((address_space(3))) void*)l,
      16, 0, 0);
}

// ------------------------------------------------------------------
// One-time: bf16-convert 6 weights; (w_al + I) -> f16. out = 7 x [256][256].
// ------------------------------------------------------------------
__global__ __launch_bounds__(256) void prep_weights(
    const float* __restrict__ w0, const float* __restrict__ w1,
    const float* __restrict__ w2, const float* __restrict__ w3,
    const float* __restrict__ w4, const float* __restrict__ w5,
    const float* __restrict__ wal, unsigned short* __restrict__ out)
{
  const int bi = blockIdx.x;               // 7*32
  const int m = bi >> 5;
  const int off = ((bi & 31) * 256 + threadIdx.x) * 8;
  const float* src = m==0?w0: m==1?w1: m==2?w2: m==3?w3: m==4?w4: m==5?w5: wal;
  f32x4 a = *(const f32x4*)(src + off);
  f32x4 b = *(const f32x4*)(src + off + 4);
  if (m == 6) {                            // fold residual (+I), store f16
    const int e = off >> 8, d = off & 255;
#pragma unroll
    for (int jj = 0; jj < 4; ++jj) {
      if (e == d + jj)     a[jj] += 1.0f;
      if (e == d + 4 + jj) b[jj] += 1.0f;
    }
    half8 h;
#pragma unroll
    for (int jj = 0; jj < 4; ++jj) {
      h[jj]     = (_Float16)a[jj];
      h[jj + 4] = (_Float16)b[jj];
    }
    *(half8*)(out + (size_t)m * 65536 + off) = h;
  } else {
    *(short8*)(out + (size_t)m * 65536 + off) = cvt8(a, b);
  }
}

// ------------------------------------------------------------------
// out[1024,256] = A @ Wbf^T (+res1)(+res2). grid 256 = 64 rowblk x 4 colblk.
// ------------------------------------------------------------------
__global__ __launch_bounds__(256) void linear_bf(
    const float* __restrict__ A, const unsigned short* __restrict__ Wbf,
    const float* __restrict__ res1, const float* __restrict__ res2,
    float* __restrict__ out)
{
  const int bi = blockIdx.x;
  const int rb = (bi >> 2) * 16;
  const int cb = (bi & 3) * 64;
  const int tid = threadIdx.x;
  const int wv = tid >> 6, lane = tid & 63;
  const int g = lane >> 4, c = lane & 15;
  const int arow = rb + c;
  const int wrow = cb + wv * 16 + c;

  f32x4 acc = (f32x4){0.f, 0.f, 0.f, 0.f};
#pragma unroll
  for (int ks = 0; ks < 8; ++ks) {
    const int d0 = ks * 32 + g * 8;
    f32x4 a0 = *(const f32x4*)(A + arow * DD + d0);
    f32x4 a1 = *(const f32x4*)(A + arow * DD + d0 + 4);
    short8 av = cvt8(a0, a1);
    short8 bv = *(const short8*)(Wbf + wrow * DD + d0);
    acc = __builtin_amdgcn_mfma_f32_16x16x32_bf16(av, bv, acc, 0, 0, 0);
  }
#pragma unroll
  for (int j = 0; j < 4; ++j) {
    const int ro = rb + g * 4 + j;
    const int co = cb + wv * 16 + c;
    float v = acc[j];
    if (res1) v += res1[ro * DD + co];
    if (res2) v += res2[ro * DD + co];
    out[ro * DD + co] = v;
  }
}

// ------------------------------------------------------------------
// q = f16((X + X@Wq^T)*log2e);  k,v = f16(X + X@{Wk,Wv}^T)
// ------------------------------------------------------------------
__global__ __launch_bounds__(256) void linear_qkv(
    const float* __restrict__ X,
    const unsigned short* __restrict__ Wq, const unsigned short* __restrict__ Wk,
    const unsigned short* __restrict__ Wv,
    _Float16* __restrict__ qout, _Float16* __restrict__ kout,
    _Float16* __restrict__ vout)
{
  const int bi = blockIdx.x;
  const int rb = (bi >> 2) * 16;
  const int cb = (bi & 3) * 64;
  const int tid = threadIdx.x;
  const int wv = tid >> 6, lane = tid & 63;
  const int g = lane >> 4, c = lane & 15;
  const int arow = rb + c;
  const int wrow = cb + wv * 16 + c;

  f32x4 aq = (f32x4){0.f,0.f,0.f,0.f};
  f32x4 ak = (f32x4){0.f,0.f,0.f,0.f};
  f32x4 av_ = (f32x4){0.f,0.f,0.f,0.f};
#pragma unroll
  for (int ks = 0; ks < 8; ++ks) {
    const int d0 = ks * 32 + g * 8;
    f32x4 a0 = *(const f32x4*)(X + arow * DD + d0);
    f32x4 a1 = *(const f32x4*)(X + arow * DD + d0 + 4);
    short8 af = cvt8(a0, a1);
    short8 bq = *(const short8*)(Wq + wrow * DD + d0);
    aq = __builtin_amdgcn_mfma_f32_16x16x32_bf16(af, bq, aq, 0, 0, 0);
    short8 bk = *(const short8*)(Wk + wrow * DD + d0);
    ak = __builtin_amdgcn_mfma_f32_16x16x32_bf16(af, bk, ak, 0, 0, 0);
    short8 bv = *(const short8*)(Wv + wrow * DD + d0);
    av_ = __builtin_amdgcn_mfma_f32_16x16x32_bf16(af, bv, av_, 0, 0, 0);
  }
#pragma unroll
  for (int j = 0; j < 4; ++j) {
    const int ro = rb + g * 4 + j;
    const int co = cb + wv * 16 + c;
    const float base = X[ro * DD + co];
    qout[ro * DD + co] = (_Float16)((base + aq[j]) * LOG2E);
    kout[ro * DD + co] = (_Float16)(base + ak[j]);
    vout[ro * DD + co] = (_Float16)(base + av_[j]);
  }
}

// ------------------------------------------------------------------
// Pack k,v (f16, [b][s][d]) into fragment order.
// k (ids 0..32767): id = b*16384 + t2*512 + ks*64 + lane -> 8 f16:
//   k[b][t2*16 + (lane&15)][ks*32 + (lane>>4)*8 + 0..7]
// v (ids 32768..98303): id2 = b*32768 + t2*1024 + slice*128 + i*64 + lane
//   -> 4 f16: v[b][t2*16 + (lane&15)][slice*32 + i*16 + (lane>>4)*4 + 0..3]
// ------------------------------------------------------------------
__global__ __launch_bounds__(256) void pack_kv(
    const _Float16* __restrict__ k, const _Float16* __restrict__ v,
    _Float16* __restrict__ kfrag, _Float16* __restrict__ vfrag)
{
  const int id = blockIdx.x * 256 + threadIdx.x;   // 98304
  if (id < 32768) {
    const int lane = id & 63, ks = (id >> 6) & 7, t2 = (id >> 9) & 31, b = id >> 14;
    const int g = lane >> 4, c = lane & 15;
    const _Float16* src = k + ((size_t)(b * SS + t2 * 16 + c) * DD + ks * 32 + g * 8);
    *(half8*)(kfrag + (size_t)id * 8) = *(const half8*)src;
  } else {
    const int id2 = id - 32768;                    // 0..65535
    const int lane = id2 & 63, i = (id2 >> 6) & 1, slice = (id2 >> 7) & 7,
              t2 = (id2 >> 10) & 31, b = id2 >> 15;
    const int g = lane >> 4, c = lane & 15;
    const _Float16* src = v + ((size_t)(b * SS + t2 * 16 + c) * DD + slice * 32 + i * 16 + g * 4);
    *(half4*)(vfrag + (size_t)id2 * 4) = *(const half4*)src;
  }
}

// ------------------------------------------------------------------
// Fused fractal attention v11. Grid 2048 = b x sq x eh; 4 waves (256 thr).
// slice = eh*4+wv owns e in [slice*32, +32). k tiles (8KB fragment-linear)
// staged to LDS (double-buffered) via straight global_load_lds; all waves
// broadcast-read conflict-free. T15: accA/accB 2-tile pipeline, UPDATE(t-1)
// under MFMA(t). launch_bounds(256,3) -> 3 waves/SIMD (live ~156 regs).
// ------------------------------------------------------------------
__global__ __launch_bounds__(256, 3) void fractal_attn(
    const _Float16* __restrict__ walI,   // f16 (wal+I), [256][256]
    const _Float16* __restrict__ qf,     // f16, pre-scaled by log2e
    const _Float16* __restrict__ kfrag,  // f16 fragment-packed
    const _Float16* __restrict__ vfrag,  // f16 fragment-packed (slice-32)
    float* __restrict__ vsum)
{
  __shared__ _Float16 kt[2][4096];       // 2 x 8KB k tiles

  const int bid = blockIdx.x;            // 2048
  const int eh = bid & 1;
  const int sq = (bid >> 1) & 511;
  const int b  = bid >> 10;
  const int tid = threadIdx.x;
  const int wv = tid >> 6;
  const int lane = tid & 63;
  const int g = lane >> 4, c = lane & 15;
  const int slice = eh * 4 + wv;
  const int sbase = slice * 32;

  // ---- k tile staging: straight linear copy, 256 thr x 2 x 16B = 8KB ----
  const _Float16* ktile0 = kfrag + (size_t)b * 131072;
  auto stage = [&](int t) {
    const _Float16* src = ktile0 + (size_t)t * 4096;
    _Float16* dst = &kt[t & 1][0];
    gload16(src + tid * 8,        dst + tid * 8);
    gload16(src + 2048 + tid * 8, dst + 2048 + tid * 8);
  };

  stage(0);   // completes while we build A'

  // ---- A' fragments: wave owns e in [sbase, sbase+32) ----
  half8 afrag[2][8];
  {
    const _Float16* qrow = qf + (size_t)(b * SS + sq) * DD;
    half8 q8[8];
#pragma unroll
    for (int ks = 0; ks < 8; ++ks)
      q8[ks] = *(const half8*)(qrow + ks * 32 + g * 8);
#pragma unroll
    for (int i = 0; i < 2; ++i) {
      const int e = sbase + i * 16 + c;
      const _Float16* wrow = walI + (size_t)e * DD;
#pragma unroll
      for (int ks = 0; ks < 8; ++ks)
        afrag[i][ks] = (*(const half8*)(wrow + ks * 32 + g * 8)) * q8[ks];
    }
  }

  // ---- v fragment base (f16): half off = b*131072 + t2*4096 + slice*512
  //      + i*256 + lane*4 ----
  const _Float16* vfb = vfrag + (size_t)b * 131072 + slice * 512 + lane * 4;

  // ---- state: 8 e-slots per lane (e = sbase + i*16 + g*4 + j) ----
  float mst[8], sst[8], vst[8];
#pragma unroll
  for (int s = 0; s < 8; ++s) { mst[s] = -1e30f; sst[s] = 0.f; vst[s] = 0.f; }

  half8 bf[8];
  half4 vqA[2], vqB[2];
  f32x4 accA[2], accB[2];
  const f32x4 zeroc = (f32x4){0.f, 0.f, 0.f, 0.f};

#define DSREAD(BUF)                                                 \
  {                                                                 \
    const _Float16* kb_ = &kt[BUF][0];                              \
    _Pragma("unroll")                                               \
    for (int ks = 0; ks < 8; ++ks)                                  \
      bf[ks] = *(const half8*)(kb_ + ks * 512 + lane * 8);          \
  }
#define LOADV(T2, VQ)                                               \
  {                                                                 \
    const _Float16* vf_ = vfb + (size_t)(T2) * 4096;                \
    VQ[0] = *(const half4*)(vf_);                                   \
    VQ[1] = *(const half4*)(vf_ + 256);                             \
  }
#define MFMA_INTO(ACC)                                              \
  {                                                                 \
    __builtin_amdgcn_s_setprio(1);                                  \
    ACC[0] = __builtin_amdgcn_mfma_f32_16x16x32_f16(                \
        afrag[0][0], bf[0], zeroc, 0, 0, 0);                        \
    ACC[1] = __builtin_amdgcn_mfma_f32_16x16x32_f16(                \
        afrag[1][0], bf[0], zeroc, 0, 0, 0);                        \
    _Pragma("unroll")                                               \
    for (int ks = 1; ks < 8; ++ks) {                                \
      ACC[0] = __builtin_amdgcn_mfma_f32_16x16x32_f16(              \
          afrag[0][ks], bf[ks], ACC[0], 0, 0, 0);                   \
      ACC[1] = __builtin_amdgcn_mfma_f32_16x16x32_f16(              \
          afrag[1][ks], bf[ks], ACC[1], 0, 0, 0);                   \
    }                                                               \
    __builtin_amdgcn_s_setprio(0);                                  \
  }
#define UPDATE(ACC, VQ)                                             \
  {                                                                 \
    _Pragma("unroll")                                               \
    for (int i = 0; i < 2; ++i)                                     \
      _Pragma("unroll")                                             \
      for (int j = 0; j < 4; ++j) {                                 \
        const int s = i * 4 + j;                                    \
        const float L = ACC[i][j];                                  \
        mst[s] = fmaxf(mst[s], L);                                  \
        const float p = L * __builtin_amdgcn_exp2f(L);              \
        sst[s] += fabsf(p);                                         \
        vst[s] = fmaf((float)VQ[i][j], p, vst[s]);                  \
      }                                                             \
  }

  // ---- prologue ----
  LOADV(0, vqA);
  __syncthreads();            // stage(0) complete
  DSREAD(0);
  stage(1);
  MFMA_INTO(accA);            // tile 0

#pragma unroll 1
  for (int t = 1; t < 31; t += 2) {
    __syncthreads();          // stage(t) complete; buf[(t+1)&1] free
    DSREAD(t & 1);
    LOADV(t, vqB);
    stage(t + 1);
    MFMA_INTO(accB);          // tile t
    UPDATE(accA, vqA);        // tile t-1 (overlaps MFMA pipe)

    __syncthreads();          // stage(t+1) complete
    DSREAD((t + 1) & 1);
    LOADV(t + 1, vqA);
    if (t + 2 < 32) stage(t + 2);
    MFMA_INTO(accA);          // tile t+1
    UPDATE(accB, vqB);        // tile t
  }

  // ---- epilogue: tile 31 ----
  __syncthreads();            // stage(31) complete
  DSREAD(1);
  LOADV(31, vqB);
  MFMA_INTO(accB);            // tile 31
  UPDATE(accA, vqA);          // tile 30
  UPDATE(accB, vqB);          // tile 31

#undef DSREAD
#undef LOADV
#undef MFMA_INTO
#undef UPDATE

  // ---- merge across the 16 sk-lanes (same g => same e) ----
#pragma unroll
  for (int mask = 1; mask <= 8; mask <<= 1) {
#pragma unroll
    for (int s = 0; s < 8; ++s) {
      mst[s] = fmaxf(mst[s], __shfl_xor(mst[s], mask));
      sst[s] += __shfl_xor(sst[s], mask);
      vst[s] += __shfl_xor(vst[s], mask);
    }
  }

  if (c == 0) {
    float* orow = vsum + (size_t)(b * SS + sq) * DD;
#pragma unroll
    for (int i = 0; i < 2; ++i) {
      f32x4 o;
#pragma unroll
      for (int j = 0; j < 4; ++j) {
        const int s = i * 4 + j;
        const float tt = LN2 * __builtin_amdgcn_exp2f(-mst[s]);
        o[j] = vst[s] * tt / (sst[s] * tt + 1.0f);
      }
      *(f32x4*)(orow + sbase + i * 16 + g * 4) = o;
    }
  }
}

// ------------------------------------------------------------------
extern "C" void kernel_launch(void* const* d_in, const int* in_sizes, int n_in,
                              void* d_out, int out_size, void* d_ws, size_t ws_size,
                              hipStream_t stream) {
  const float* x     = (const float*)d_in[0];
  const float* w_pre = (const float*)d_in[1];
  const float* w_q   = (const float*)d_in[2];
  const float* w_k   = (const float*)d_in[3];
  const float* w_va  = (const float*)d_in[4];
  const float* w_al  = (const float*)d_in[5];
  const float* w_vo  = (const float*)d_in[6];
  const float* w_end = (const float*)d_in[7];
  float* out = (float*)d_out;

  char* ws = (char*)d_ws;
  float*    X     = (float*)(ws);                         // 1MB
  float*    Y     = (float*)(ws + (1 << 20));             // 1MB
  float*    vsum  = (float*)(ws + (2 << 20));             // 1MB
  _Float16* qf16  = (_Float16*)(ws + (3 << 20));          // 512KB
  _Float16* kf16  = (_Float16*)(ws + (3 << 20) + (512 << 10));
  _Float16* vf16  = (_Float16*)(ws + (4 << 20));
  _Float16* kfrag = (_Float16*)(ws + (4 << 20) + (512 << 10));  // 512KB
  _Float16* vfrag = (_Float16*)(ws + (5 << 20));                // 512KB
  unsigned short* wbf = (unsigned short*)(ws + (5 << 20) + (512 << 10));
  // wbf order: pre, q, k, va, vo, end, walI(+I, f16)

  prep_weights<<<224, 256, 0, stream>>>(w_pre, w_q, w_k, w_va, w_vo, w_end,
                                        w_al, wbf);
  linear_bf<<<256, 256, 0, stream>>>(x, wbf + 0 * 65536, nullptr, nullptr, X);
  linear_qkv<<<256, 256, 0, stream>>>(X, wbf + 1 * 65536, wbf + 2 * 65536,
                                      wbf + 3 * 65536, qf16, kf16, vf16);
  pack_kv<<<384, 256, 0, stream>>>(kf16, vf16, kfrag, vfrag);
  fractal_attn<<<2048, 256, 0, stream>>>((const _Float16*)(wbf + 6 * 65536),
                                         qf16, kfrag, vfrag, vsum);
  linear_bf<<<256, 256, 0, stream>>>(vsum, wbf + 4 * 65536, vsum, X, Y);
  linear_bf<<<256, 256, 0, stream>>>(Y, wbf + 5 * 65536, nullptr, nullptr, out);
}